// Round 3
// baseline (968.144 us; speedup 1.0000x reference)
//
#include <hip/hip_runtime.h>
#include <hip/hip_bf16.h>
#include <math.h>

#define BATCH  4
#define SEQ    4096
#define DMODEL 2048
#define DSTATE 64
#define DINNER 1024
#define MTOT   (BATCH*SEQ)          // 16384
#define NPROJ  (DINNER+DINNER+DSTATE+DSTATE) // 2176
#define CH     128                  // scan chunk length
#define NC     (SEQ/CH)             // 32 chunks

typedef __attribute__((ext_vector_type(8))) short bf16x8;   // 8 bf16 = 4 VGPR
typedef __attribute__((ext_vector_type(4))) float f32x4;

// ---------------------------------------------------------------------------
// fp32 -> (hi, lo) bf16 split using HW converts (v_cvt_pk_bf16_f32 pairs).
// v ~= hi + lo, |v - hi - lo| <= ~2^-17 |v|.
// ---------------------------------------------------------------------------
__device__ __forceinline__ unsigned short f2bf(float v) {
    __hip_bfloat16 b = __float2bfloat16(v);
    unsigned short u; __builtin_memcpy(&u, &b, 2); return u;
}
__device__ __forceinline__ float bf2f(unsigned short u) {
    __hip_bfloat16 b; __builtin_memcpy(&b, &u, 2); return __bfloat162float(b);
}
__device__ __forceinline__ void split2(float v, unsigned short& h, unsigned short& l) {
    h = f2bf(v);
    l = f2bf(v - bf2f(h));   // residual exact in fp32 (Sterbenz), then RNE
}

// ---------------------------------------------------------------------------
// Projection GEMM: C[m,n] = sum_k X[m,k] * W_all[n,k]
//   X fp32, reg-staged + split (hi/lo bf16) into LDS in-kernel
//   W pre-split bf16 hi/lo (packed rows: Wx|Wdt|WB|WC), global_load_lds 16B
// 128x128 tile, BK=32, 4 waves (2x2), 16x16x32 bf16 MFMA, 3 products (hh,hl,lh).
// Epilogue scatters to x_ssm / dt(=softplus+clip fused) / Bm / Cm.
// ---------------------------------------------------------------------------
__global__ __launch_bounds__(256, 2)
void proj_gemm(const float* __restrict__ X,
               const unsigned short* __restrict__ Wh,
               const unsigned short* __restrict__ Wl,
               const float* __restrict__ b_dt,
               float* __restrict__ x_ssm, float* __restrict__ dt,
               float* __restrict__ Bm,    float* __restrict__ Cm)
{
    __shared__ unsigned short Ahs[128*32];
    __shared__ unsigned short Als[128*32];
    __shared__ unsigned short Bhs[128*32];
    __shared__ unsigned short Bls[128*32];

    const int tid  = threadIdx.x;
    const int lane = tid & 63;
    const int w    = tid >> 6;
    const int wr   = (w >> 1) * 64;
    const int wc   = (w & 1)  * 64;
    const int l15  = lane & 15;
    const int lg   = lane >> 4;
    const int nblk = blockIdx.x * 128;
    const int mblk = blockIdx.y * 128;

    f32x4 acc[4][4];
    #pragma unroll
    for (int m = 0; m < 4; ++m)
        #pragma unroll
        for (int n = 0; n < 4; ++n)
            acc[m][n] = (f32x4){0.f, 0.f, 0.f, 0.f};

    for (int k0 = 0; k0 < DMODEL; k0 += 32) {
        // A tile 128x32 fp32 -> regs (1024 16B-segs, 4/thread), before barrier
        float4 av[4];
        #pragma unroll
        for (int r = 0; r < 4; ++r) {
            int s   = r * 256 + tid;
            int row = s >> 3, seg = s & 7;
            av[r] = *reinterpret_cast<const float4*>(
                &X[(size_t)(mblk + row) * DMODEL + k0 + seg * 4]);
        }
        __syncthreads();   // previous iteration's fragment reads complete
        // split + ds_write hi/lo (HW cvt)
        #pragma unroll
        for (int r = 0; r < 4; ++r) {
            int s   = r * 256 + tid;
            int row = s >> 3, seg = s & 7;
            unsigned short h0,h1,h2,h3,l0,l1,l2,l3;
            split2(av[r].x, h0, l0); split2(av[r].y, h1, l1);
            split2(av[r].z, h2, l2); split2(av[r].w, h3, l3);
            *reinterpret_cast<ushort4*>(&Ahs[row*32 + seg*4]) = make_ushort4(h0,h1,h2,h3);
            *reinterpret_cast<ushort4*>(&Als[row*32 + seg*4]) = make_ushort4(l0,l1,l2,l3);
        }
        // W tiles hi/lo via async global->LDS (16B, linear dest; 512 segs each)
        #pragma unroll
        for (int r = 0; r < 2; ++r) {
            int s    = r * 256 + tid;
            int row  = s >> 2, kseg = s & 3;
            const unsigned short* srch = &Wh[(size_t)(nblk + row) * DMODEL + k0 + kseg * 8];
            const unsigned short* srcl = &Wl[(size_t)(nblk + row) * DMODEL + k0 + kseg * 8];
            unsigned short* dsth = &Bhs[(size_t)(r * 256 + w * 64) * 8]; // wave-uniform base
            unsigned short* dstl = &Bls[(size_t)(r * 256 + w * 64) * 8];
            __builtin_amdgcn_global_load_lds(
                (const __attribute__((address_space(1))) void*)srch,
                (__attribute__((address_space(3))) void*)dsth, 16, 0, 0);
            __builtin_amdgcn_global_load_lds(
                (const __attribute__((address_space(1))) void*)srcl,
                (__attribute__((address_space(3))) void*)dstl, 16, 0, 0);
        }
        __syncthreads();   // drains lgkm (ds_write) + vmcnt (gload_lds)

        // fragments: lane -> row = l&15, k-group = l>>4 (consistent bijection)
        bf16x8 af[4][2], bfr[4][2];
        #pragma unroll
        for (int m = 0; m < 4; ++m) {
            int row = wr + m * 16 + l15;
            af[m][0] = *reinterpret_cast<const bf16x8*>(&Ahs[row*32 + lg*8]);
            af[m][1] = *reinterpret_cast<const bf16x8*>(&Als[row*32 + lg*8]);
        }
        #pragma unroll
        for (int n = 0; n < 4; ++n) {
            int row = wc + n * 16 + l15;
            bfr[n][0] = *reinterpret_cast<const bf16x8*>(&Bhs[row*32 + lg*8]);
            bfr[n][1] = *reinterpret_cast<const bf16x8*>(&Bls[row*32 + lg*8]);
        }
        #pragma unroll
        for (int m = 0; m < 4; ++m)
            #pragma unroll
            for (int n = 0; n < 4; ++n) {
                acc[m][n] = __builtin_amdgcn_mfma_f32_16x16x32_bf16(af[m][0], bfr[n][0], acc[m][n], 0, 0, 0);
                acc[m][n] = __builtin_amdgcn_mfma_f32_16x16x32_bf16(af[m][0], bfr[n][1], acc[m][n], 0, 0, 0);
                acc[m][n] = __builtin_amdgcn_mfma_f32_16x16x32_bf16(af[m][1], bfr[n][0], acc[m][n], 0, 0, 0);
            }
    }

    // epilogue: C/D layout col=lane&15, row=(lane>>4)*4+reg (HW-verified m89/m91)
    #pragma unroll
    for (int m = 0; m < 4; ++m) {
        #pragma unroll
        for (int n = 0; n < 4; ++n) {
            #pragma unroll
            for (int q = 0; q < 4; ++q) {
                int gm = mblk + wr + m * 16 + lg * 4 + q;
                int gn = nblk + wc + n * 16 + l15;
                float v = acc[m][n][q];
                if (gn < 1024) {
                    x_ssm[(size_t)gm * DINNER + gn] = v;
                } else if (gn < 2048) {
                    float z  = v + b_dt[gn - 1024];
                    float sp = z > 15.f ? z : log1pf(expf(z));
                    dt[(size_t)gm * DINNER + (gn - 1024)] =
                        fminf(fmaxf(sp, 1e-4f), 0.5f);
                } else if (gn < 2112) {
                    Bm[(size_t)gm * DSTATE + (gn - 2048)] = v;
                } else {
                    Cm[(size_t)gm * DSTATE + (gn - 2112)] = v;
                }
            }
        }
    }
}

// ---------------------------------------------------------------------------
// Output GEMM, fully pre-split operands: C[m,o] = sum_i Y[m,i] * Wout[o,i]
// Both A (Yh/Yl) and B (Woh/Wol) staged via global_load_lds; no split VALU.
// ---------------------------------------------------------------------------
__global__ __launch_bounds__(256, 2)
void out_gemm(const unsigned short* __restrict__ Yh, const unsigned short* __restrict__ Yl,
              const unsigned short* __restrict__ Woh, const unsigned short* __restrict__ Wol,
              float* __restrict__ Out)
{
    __shared__ unsigned short Ahs[128*32];
    __shared__ unsigned short Als[128*32];
    __shared__ unsigned short Bhs[128*32];
    __shared__ unsigned short Bls[128*32];

    const int tid  = threadIdx.x;
    const int lane = tid & 63;
    const int w    = tid >> 6;
    const int wr   = (w >> 1) * 64;
    const int wc   = (w & 1)  * 64;
    const int l15  = lane & 15;
    const int lg   = lane >> 4;
    const int nblk = blockIdx.x * 128;
    const int mblk = blockIdx.y * 128;

    f32x4 acc[4][4];
    #pragma unroll
    for (int m = 0; m < 4; ++m)
        #pragma unroll
        for (int n = 0; n < 4; ++n)
            acc[m][n] = (f32x4){0.f, 0.f, 0.f, 0.f};

    for (int k0 = 0; k0 < DINNER; k0 += 32) {
        __syncthreads();   // previous iteration's fragment reads complete
        #pragma unroll
        for (int r = 0; r < 2; ++r) {
            int s    = r * 256 + tid;
            int row  = s >> 2, kseg = s & 3;
            size_t aoff = (size_t)(mblk + row) * DINNER + k0 + kseg * 8;
            size_t boff = (size_t)(nblk + row) * DINNER + k0 + kseg * 8;
            unsigned short* dbase_a_h = &Ahs[(size_t)(r * 256 + w * 64) * 8];
            unsigned short* dbase_a_l = &Als[(size_t)(r * 256 + w * 64) * 8];
            unsigned short* dbase_b_h = &Bhs[(size_t)(r * 256 + w * 64) * 8];
            unsigned short* dbase_b_l = &Bls[(size_t)(r * 256 + w * 64) * 8];
            __builtin_amdgcn_global_load_lds(
                (const __attribute__((address_space(1))) void*)&Yh[aoff],
                (__attribute__((address_space(3))) void*)dbase_a_h, 16, 0, 0);
            __builtin_amdgcn_global_load_lds(
                (const __attribute__((address_space(1))) void*)&Yl[aoff],
                (__attribute__((address_space(3))) void*)dbase_a_l, 16, 0, 0);
            __builtin_amdgcn_global_load_lds(
                (const __attribute__((address_space(1))) void*)&Woh[boff],
                (__attribute__((address_space(3))) void*)dbase_b_h, 16, 0, 0);
            __builtin_amdgcn_global_load_lds(
                (const __attribute__((address_space(1))) void*)&Wol[boff],
                (__attribute__((address_space(3))) void*)dbase_b_l, 16, 0, 0);
        }
        __syncthreads();

        bf16x8 af[4][2], bfr[4][2];
        #pragma unroll
        for (int m = 0; m < 4; ++m) {
            int row = wr + m * 16 + l15;
            af[m][0] = *reinterpret_cast<const bf16x8*>(&Ahs[row*32 + lg*8]);
            af[m][1] = *reinterpret_cast<const bf16x8*>(&Als[row*32 + lg*8]);
        }
        #pragma unroll
        for (int n = 0; n < 4; ++n) {
            int row = wc + n * 16 + l15;
            bfr[n][0] = *reinterpret_cast<const bf16x8*>(&Bhs[row*32 + lg*8]);
            bfr[n][1] = *reinterpret_cast<const bf16x8*>(&Bls[row*32 + lg*8]);
        }
        #pragma unroll
        for (int m = 0; m < 4; ++m)
            #pragma unroll
            for (int n = 0; n < 4; ++n) {
                acc[m][n] = __builtin_amdgcn_mfma_f32_16x16x32_bf16(af[m][0], bfr[n][0], acc[m][n], 0, 0, 0);
                acc[m][n] = __builtin_amdgcn_mfma_f32_16x16x32_bf16(af[m][0], bfr[n][1], acc[m][n], 0, 0, 0);
                acc[m][n] = __builtin_amdgcn_mfma_f32_16x16x32_bf16(af[m][1], bfr[n][0], acc[m][n], 0, 0, 0);
            }
    }

    #pragma unroll
    for (int m = 0; m < 4; ++m) {
        #pragma unroll
        for (int n = 0; n < 4; ++n) {
            #pragma unroll
            for (int q = 0; q < 4; ++q) {
                size_t gm = mblk + wr + m * 16 + lg * 4 + q;
                int    gn = nblk + wc + n * 16 + l15;
                Out[gm * DINNER + gn] = acc[m][n][q];
            }
        }
    }
}

// ---------------------------------------------------------------------------
// fp32 -> hi/lo bf16 split (weights), float4 grid-stride
// ---------------------------------------------------------------------------
__global__ void split_f32(const float* __restrict__ src, unsigned short* __restrict__ h,
                          unsigned short* __restrict__ l, int n4)
{
    int stride = gridDim.x * blockDim.x;
    for (int i = blockIdx.x * blockDim.x + threadIdx.x; i < n4; i += stride) {
        float4 v = reinterpret_cast<const float4*>(src)[i];
        unsigned short h0,h1,h2,h3,l0,l1,l2,l3;
        split2(v.x, h0, l0); split2(v.y, h1, l1);
        split2(v.z, h2, l2); split2(v.w, h3, l3);
        reinterpret_cast<ushort4*>(h)[i] = make_ushort4(h0,h1,h2,h3);
        reinterpret_cast<ushort4*>(l)[i] = make_ushort4(l0,l1,l2,l3);
    }
}

// ---------------------------------------------------------------------------
// Row-normalize Bm and Cm: row /= max(||row||, 1). One wave per (row, matrix).
// ---------------------------------------------------------------------------
__global__ void normalize_bc(float* __restrict__ Bm, float* __restrict__ Cm)
{
    int w    = (blockIdx.x * blockDim.x + threadIdx.x) >> 6;
    int lane = threadIdx.x & 63;
    int row  = w >> 1;
    float* M = (w & 1) ? Cm : Bm;
    float v = M[(size_t)row * DSTATE + lane];
    float s = v * v;
    #pragma unroll
    for (int off = 32; off; off >>= 1) s += __shfl_xor(s, off);
    float scale = 1.0f / fmaxf(sqrtf(s), 1.0f);
    M[(size_t)row * DSTATE + lane] = v * scale;
}

// ---------------------------------------------------------------------------
// Scan pass A: per-chunk (A_prod, P) summaries per channel.
// grid: (b,c,ib) = 4*32*4 = 512 blocks x 256 threads.
// ---------------------------------------------------------------------------
__global__ void scan_passA(const float* __restrict__ dt, const float* __restrict__ x_ssm,
                           const float* __restrict__ Bm, const float* __restrict__ A_log,
                           float* __restrict__ Asum, float* __restrict__ Psum)
{
    int bi = blockIdx.x;
    int ib = bi & 3;
    int c  = (bi >> 2) & (NC - 1);
    int b  = bi >> 7;
    int i  = ib * 256 + threadIdx.x;
    float aneg = -expf(A_log[i]);
    float Aacc = 1.0f, P = 0.0f;
    size_t rowbase = (size_t)b * SEQ + (size_t)c * CH;
    for (int t = 0; t < CH; ++t) {
        size_t off = (rowbase + t) * DINNER + i;
        float d  = dt[off];
        float x  = x_ssm[off];
        float Bv = Bm[(rowbase + t) * DSTATE + (i & 63)];
        float a  = expf(d * aneg);
        Aacc *= a;
        P = fmaf(a, P, d * Bv * x);
    }
    size_t so = ((size_t)b * NC + c) * DINNER + i;
    Asum[so] = Aacc; Psum[so] = P;
}

// ---------------------------------------------------------------------------
// Chunk-prefix: sequential over NC=32 chunk summaries per channel.
// ---------------------------------------------------------------------------
__global__ void scan_chunkprefix(const float* __restrict__ Asum,
                                 const float* __restrict__ Psum,
                                 float* __restrict__ H)
{
    int idx = blockIdx.x * blockDim.x + threadIdx.x; // 0..4095
    int b = idx >> 10, i = idx & 1023;
    float h = 0.0f;
    for (int c = 0; c < NC; ++c) {
        size_t so = ((size_t)b * NC + c) * DINNER + i;
        H[so] = h;
        h = fmaf(Asum[so], h, Psum[so]);
    }
}

// ---------------------------------------------------------------------------
// Scan pass B: replay with h_start; y = C*h + Dp*x_ssm, written pre-split
// as bf16 hi/lo (feeds out_gemm directly).
// ---------------------------------------------------------------------------
__global__ void scan_passB(const float* __restrict__ dt, const float* __restrict__ x_ssm,
                           const float* __restrict__ Bm, const float* __restrict__ Cm,
                           const float* __restrict__ A_log, const float* __restrict__ Dp,
                           const float* __restrict__ H,
                           unsigned short* __restrict__ Yh, unsigned short* __restrict__ Yl)
{
    int bi = blockIdx.x;
    int ib = bi & 3;
    int c  = (bi >> 2) & (NC - 1);
    int b  = bi >> 7;
    int i  = ib * 256 + threadIdx.x;
    float aneg = -expf(A_log[i]);
    float Dpi  = Dp[i];
    size_t so = ((size_t)b * NC + c) * DINNER + i;
    float h = H[so];
    size_t rowbase = (size_t)b * SEQ + (size_t)c * CH;
    for (int t = 0; t < CH; ++t) {
        size_t off = (rowbase + t) * DINNER + i;
        float d  = dt[off];
        float x  = x_ssm[off];
        float Bv = Bm[(rowbase + t) * DSTATE + (i & 63)];
        float Cv = Cm[(rowbase + t) * DSTATE + (i & 63)];
        float a  = expf(d * aneg);
        h = fmaf(a, h, d * Bv * x);
        float y = Cv * h + Dpi * x;
        unsigned short yh, yl;
        split2(y, yh, yl);
        Yh[off] = yh; Yl[off] = yl;
    }
}

// ---------------------------------------------------------------------------
extern "C" void kernel_launch(void* const* d_in, const int* in_sizes, int n_in,
                              void* d_out, int out_size, void* d_ws, size_t ws_size,
                              hipStream_t stream)
{
    const float* x_norm = (const float*)d_in[0];
    const float* Wx     = (const float*)d_in[1];
    const float* Wdt    = (const float*)d_in[2];
    const float* b_dt   = (const float*)d_in[3];
    const float* WB     = (const float*)d_in[4];
    const float* WC     = (const float*)d_in[5];
    const float* A_log  = (const float*)d_in[6];
    const float* Dp     = (const float*)d_in[7];
    const float* Wout   = (const float*)d_in[8];
    float* out = (float*)d_out;

    const size_t MB = 1024 * 1024;
    char* ws = (char*)d_ws;
    float* x_ssm = (float*)(ws);                         // [0,64) MB
    float* dtbuf = (float*)(ws + 64*MB);                 // [64,128) MB
    float* Bm    = (float*)(ws + 128*MB);                // 4 MB
    float* Cm    = (float*)(ws + 132*MB);                // 4 MB
    float* Asum  = (float*)(ws + 136*MB);                // 512 KB
    float* Psum  = (float*)(ws + 136*MB + 512*1024);     // 512 KB
    float* Hbuf  = (float*)(ws + 137*MB);                // 512 KB
    unsigned short* Wh  = (unsigned short*)(ws + 138*MB); // 8.5 MB (2176x2048)
    unsigned short* Wl  = (unsigned short*)(ws + 147*MB); // 8.5 MB
    unsigned short* Woh = (unsigned short*)(ws + 156*MB); // 2 MB (1024x1024)
    unsigned short* Wol = (unsigned short*)(ws + 158*MB); // 2 MB
    unsigned short* Yh  = (unsigned short*)(ws + 160*MB); // 32 MB (16384x1024)
    unsigned short* Yl  = (unsigned short*)(ws + 192*MB); // 32 MB  -> total 224 MB

    const size_t WXN = (size_t)DINNER * DMODEL;   // 2M elems
    const size_t WBN = (size_t)DSTATE * DMODEL;   // 128K elems

    // 1. split weights to hi/lo bf16 (packed W_all rows: Wx|Wdt|WB|WC)
    split_f32<<<1024, 256, 0, stream>>>(Wx,  Wh,             Wl,             (int)(WXN/4));
    split_f32<<<1024, 256, 0, stream>>>(Wdt, Wh + WXN,       Wl + WXN,       (int)(WXN/4));
    split_f32<<<64,   256, 0, stream>>>(WB,  Wh + 2*WXN,     Wl + 2*WXN,     (int)(WBN/4));
    split_f32<<<64,   256, 0, stream>>>(WC,  Wh + 2*WXN+WBN, Wl + 2*WXN+WBN, (int)(WBN/4));
    split_f32<<<1024, 256, 0, stream>>>(Wout, Woh, Wol, (int)((size_t)DINNER*DINNER/4));

    // 2. fused projection GEMM (softplus+clip fused into epilogue)
    proj_gemm<<<dim3(NPROJ/128, MTOT/128), 256, 0, stream>>>(
        x_norm, Wh, Wl, b_dt, x_ssm, dtbuf, Bm, Cm);
    // 3. normalize B,C rows
    normalize_bc<<<(MTOT*2)/4, 256, 0, stream>>>(Bm, Cm);
    // 4. chunk scan summaries
    scan_passA<<<BATCH*NC*(DINNER/256), 256, 0, stream>>>(
        dtbuf, x_ssm, Bm, A_log, Asum, Psum);
    // 5. chunk prefix
    scan_chunkprefix<<<(BATCH*DINNER)/256, 256, 0, stream>>>(Asum, Psum, Hbuf);
    // 6. replay; y written pre-split bf16 hi/lo
    scan_passB<<<BATCH*NC*(DINNER/256), 256, 0, stream>>>(
        dtbuf, x_ssm, Bm, Cm, A_log, Dp, Hbuf, Yh, Yl);
    // 7. output projection GEMM (pure pre-split bf16)
    out_gemm<<<dim3(DINNER/128, MTOT/128), 256, 0, stream>>>(
        Yh, Yl, Woh, Wol, out);
}

// Round 6
// 899.641 us; speedup vs baseline: 1.0761x; 1.0761x over previous
//
#include <hip/hip_runtime.h>
#include <hip/hip_bf16.h>
#include <math.h>

#define BATCH  4
#define SEQ    4096
#define DMODEL 2048
#define DSTATE 64
#define DINNER 1024
#define MTOT   (BATCH*SEQ)          // 16384
#define NPROJ  (DINNER+DINNER+DSTATE+DSTATE) // 2176
#define CH     128                  // scan chunk length
#define NC     (SEQ/CH)             // 32 chunks

typedef __attribute__((ext_vector_type(8))) short bf16x8;   // 8 bf16 = 4 VGPR
typedef __attribute__((ext_vector_type(4))) float f32x4;

// ---------------------------------------------------------------------------
// fp32 -> (hi, lo) bf16 split using HW converts.
// v ~= hi + lo, |v - hi - lo| <= ~2^-17 |v|.
// ---------------------------------------------------------------------------
__device__ __forceinline__ unsigned short f2bf(float v) {
    __hip_bfloat16 b = __float2bfloat16(v);
    unsigned short u; __builtin_memcpy(&u, &b, 2); return u;
}
__device__ __forceinline__ float bf2f(unsigned short u) {
    __hip_bfloat16 b; __builtin_memcpy(&b, &u, 2); return __bfloat162float(b);
}
__device__ __forceinline__ void split2(float v, unsigned short& h, unsigned short& l) {
    h = f2bf(v);
    l = f2bf(v - bf2f(h));
}

// ---------------------------------------------------------------------------
// Swizzled fragment read. LDS tile = 128 rows x 32 bf16 (64 B/row, 4x16B slots).
// Slot holding global k-seg g of row r is  j = g ^ ((r>>1)&3): spreads the
// 16 rows a frag-read touches over 8 distinct 16B bank-groups -> 2-way (free).
// ---------------------------------------------------------------------------
__device__ __forceinline__ bf16x8 frag_ld(const unsigned short* buf, int row, int lg) {
    int j = lg ^ ((row >> 1) & 3);
    return *reinterpret_cast<const bf16x8*>(&buf[row * 32 + j * 8]);
}

// ---------------------------------------------------------------------------
// Projection GEMM: C[m,n] = sum_k X[m,k] * W_all[n,k]
//   X fp32 reg-staged, split hi/lo bf16, ds_write SWIZZLED
//   W pre-split bf16 hi/lo, global_load_lds 16B with SOURCE pre-swizzle
// 128x128 tile, BK=32, 4 waves (2x2), 16x16x32 bf16 MFMA, 3 products.
// XCD chunk swizzle: each XCD owns a contiguous run of m-groups.
// Epilogue scatters x_ssm / dt(softplus+clip) / Bm / Cm.
// ---------------------------------------------------------------------------
__global__ __launch_bounds__(256, 2)
void proj_gemm(const float* __restrict__ X,
               const unsigned short* __restrict__ Wh,
               const unsigned short* __restrict__ Wl,
               const float* __restrict__ b_dt,
               float* __restrict__ x_ssm, float* __restrict__ dt,
               float* __restrict__ Bm,    float* __restrict__ Cm)
{
    __shared__ unsigned short Ahs[128*32];
    __shared__ unsigned short Als[128*32];
    __shared__ unsigned short Bhs[128*32];
    __shared__ unsigned short Bls[128*32];

    const int tid  = threadIdx.x;
    const int lane = tid & 63;
    const int w    = tid >> 6;
    const int wr   = (w >> 1) * 64;
    const int wc   = (w & 1)  * 64;
    const int l15  = lane & 15;
    const int lg   = lane >> 4;

    // bijective XCD chunk swizzle (nwg = 17*128 = 2176, %8 == 0)
    const int nwg   = gridDim.x * gridDim.y;
    const int bid   = blockIdx.y * gridDim.x + blockIdx.x;
    const int swz   = (bid & 7) * (nwg >> 3) + (bid >> 3);
    const int nblk  = (swz % gridDim.x) * 128;
    const int mblk  = (swz / gridDim.x) * 128;

    f32x4 acc[4][4];
    #pragma unroll
    for (int m = 0; m < 4; ++m)
        #pragma unroll
        for (int n = 0; n < 4; ++n)
            acc[m][n] = (f32x4){0.f, 0.f, 0.f, 0.f};

    for (int k0 = 0; k0 < DMODEL; k0 += 32) {
        // A tile 128x32 fp32 -> regs, issued before barrier (overlaps prev MFMA)
        float4 av[4];
        #pragma unroll
        for (int r = 0; r < 4; ++r) {
            int s   = r * 256 + tid;
            int row = s >> 3, seg = s & 7;
            av[r] = *reinterpret_cast<const float4*>(
                &X[(size_t)(mblk + row) * DMODEL + k0 + seg * 4]);
        }
        __syncthreads();   // previous iteration's fragment reads complete
        // split + SWIZZLED ds_write hi/lo (8B granules; slot j' = (seg>>1)^((row>>1)&3))
        #pragma unroll
        for (int r = 0; r < 4; ++r) {
            int s   = r * 256 + tid;
            int row = s >> 3, seg = s & 7;
            int off = row * 32 + (((seg >> 1) ^ ((row >> 1) & 3)) * 8) + (seg & 1) * 4;
            unsigned short h0,h1,h2,h3,l0,l1,l2,l3;
            split2(av[r].x, h0, l0); split2(av[r].y, h1, l1);
            split2(av[r].z, h2, l2); split2(av[r].w, h3, l3);
            *reinterpret_cast<ushort4*>(&Ahs[off]) = make_ushort4(h0,h1,h2,h3);
            *reinterpret_cast<ushort4*>(&Als[off]) = make_ushort4(l0,l1,l2,l3);
        }
        // W tiles hi/lo via async global->LDS: linear dest, SOURCE pre-swizzled
        #pragma unroll
        for (int r = 0; r < 2; ++r) {
            int s    = r * 256 + tid;
            int row  = s >> 2, j = s & 3;
            int js   = j ^ ((row >> 1) & 3);          // global k-seg placed in slot j
            const unsigned short* srch = &Wh[(size_t)(nblk + row) * DMODEL + k0 + js * 8];
            const unsigned short* srcl = &Wl[(size_t)(nblk + row) * DMODEL + k0 + js * 8];
            unsigned short* dsth = &Bhs[(size_t)(r * 256 + w * 64) * 8]; // wave-uniform base
            unsigned short* dstl = &Bls[(size_t)(r * 256 + w * 64) * 8];
            __builtin_amdgcn_global_load_lds(
                (const __attribute__((address_space(1))) void*)srch,
                (__attribute__((address_space(3))) void*)dsth, 16, 0, 0);
            __builtin_amdgcn_global_load_lds(
                (const __attribute__((address_space(1))) void*)srcl,
                (__attribute__((address_space(3))) void*)dstl, 16, 0, 0);
        }
        __syncthreads();   // drains lgkm (ds_write) + vmcnt (gload_lds)

        bf16x8 af[4][2], bfr[4][2];
        #pragma unroll
        for (int m = 0; m < 4; ++m) {
            int row = wr + m * 16 + l15;
            af[m][0] = frag_ld(Ahs, row, lg);
            af[m][1] = frag_ld(Als, row, lg);
        }
        #pragma unroll
        for (int n = 0; n < 4; ++n) {
            int row = wc + n * 16 + l15;
            bfr[n][0] = frag_ld(Bhs, row, lg);
            bfr[n][1] = frag_ld(Bls, row, lg);
        }
        #pragma unroll
        for (int m = 0; m < 4; ++m)
            #pragma unroll
            for (int n = 0; n < 4; ++n) {
                acc[m][n] = __builtin_amdgcn_mfma_f32_16x16x32_bf16(af[m][0], bfr[n][0], acc[m][n], 0, 0, 0);
                acc[m][n] = __builtin_amdgcn_mfma_f32_16x16x32_bf16(af[m][0], bfr[n][1], acc[m][n], 0, 0, 0);
                acc[m][n] = __builtin_amdgcn_mfma_f32_16x16x32_bf16(af[m][1], bfr[n][0], acc[m][n], 0, 0, 0);
            }
    }

    // epilogue: C/D layout col=lane&15, row=(lane>>4)*4+reg (HW-verified m89/m91)
    #pragma unroll
    for (int m = 0; m < 4; ++m) {
        #pragma unroll
        for (int n = 0; n < 4; ++n) {
            int gn = nblk + wc + n * 16 + l15;
            float bv = (gn >= 1024 && gn < 2048) ? b_dt[gn - 1024] : 0.0f;
            #pragma unroll
            for (int q = 0; q < 4; ++q) {
                int gm = mblk + wr + m * 16 + lg * 4 + q;
                float v = acc[m][n][q];
                if (gn < 1024) {
                    x_ssm[(size_t)gm * DINNER + gn] = v;
                } else if (gn < 2048) {
                    float z  = v + bv;
                    float sp = z > 15.f ? z : log1pf(expf(z));
                    dt[(size_t)gm * DINNER + (gn - 1024)] =
                        fminf(fmaxf(sp, 1e-4f), 0.5f);
                } else if (gn < 2112) {
                    Bm[(size_t)gm * DSTATE + (gn - 2048)] = v;
                } else {
                    Cm[(size_t)gm * DSTATE + (gn - 2112)] = v;
                }
            }
        }
    }
}

// ---------------------------------------------------------------------------
// Output GEMM, fully pre-split: C[m,o] = sum_i Y[m,i] * Wout[o,i]
// A (Yh/Yl) and B (Woh/Wol) via global_load_lds with source pre-swizzle.
// ---------------------------------------------------------------------------
__global__ __launch_bounds__(256, 2)
void out_gemm(const unsigned short* __restrict__ Yh, const unsigned short* __restrict__ Yl,
              const unsigned short* __restrict__ Woh, const unsigned short* __restrict__ Wol,
              float* __restrict__ Out)
{
    __shared__ unsigned short Ahs[128*32];
    __shared__ unsigned short Als[128*32];
    __shared__ unsigned short Bhs[128*32];
    __shared__ unsigned short Bls[128*32];

    const int tid  = threadIdx.x;
    const int lane = tid & 63;
    const int w    = tid >> 6;
    const int wr   = (w >> 1) * 64;
    const int wc   = (w & 1)  * 64;
    const int l15  = lane & 15;
    const int lg   = lane >> 4;

    // bijective XCD chunk swizzle (nwg = 8*128 = 1024, %8 == 0)
    const int nwg   = gridDim.x * gridDim.y;
    const int bid   = blockIdx.y * gridDim.x + blockIdx.x;
    const int swz   = (bid & 7) * (nwg >> 3) + (bid >> 3);
    const int nblk  = (swz % gridDim.x) * 128;
    const int mblk  = (swz / gridDim.x) * 128;

    f32x4 acc[4][4];
    #pragma unroll
    for (int m = 0; m < 4; ++m)
        #pragma unroll
        for (int n = 0; n < 4; ++n)
            acc[m][n] = (f32x4){0.f, 0.f, 0.f, 0.f};

    for (int k0 = 0; k0 < DINNER; k0 += 32) {
        __syncthreads();   // previous iteration's fragment reads complete
        #pragma unroll
        for (int r = 0; r < 2; ++r) {
            int s    = r * 256 + tid;
            int row  = s >> 2, j = s & 3;
            int js   = j ^ ((row >> 1) & 3);
            size_t aoff = (size_t)(mblk + row) * DINNER + k0 + js * 8;
            size_t boff = (size_t)(nblk + row) * DINNER + k0 + js * 8;
            unsigned short* da_h = &Ahs[(size_t)(r * 256 + w * 64) * 8];
            unsigned short* da_l = &Als[(size_t)(r * 256 + w * 64) * 8];
            unsigned short* db_h = &Bhs[(size_t)(r * 256 + w * 64) * 8];
            unsigned short* db_l = &Bls[(size_t)(r * 256 + w * 64) * 8];
            __builtin_amdgcn_global_load_lds(
                (const __attribute__((address_space(1))) void*)&Yh[aoff],
                (__attribute__((address_space(3))) void*)da_h, 16, 0, 0);
            __builtin_amdgcn_global_load_lds(
                (const __attribute__((address_space(1))) void*)&Yl[aoff],
                (__attribute__((address_space(3))) void*)da_l, 16, 0, 0);
            __builtin_amdgcn_global_load_lds(
                (const __attribute__((address_space(1))) void*)&Woh[boff],
                (__attribute__((address_space(3))) void*)db_h, 16, 0, 0);
            __builtin_amdgcn_global_load_lds(
                (const __attribute__((address_space(1))) void*)&Wol[boff],
                (__attribute__((address_space(3))) void*)db_l, 16, 0, 0);
        }
        __syncthreads();

        bf16x8 af[4][2], bfr[4][2];
        #pragma unroll
        for (int m = 0; m < 4; ++m) {
            int row = wr + m * 16 + l15;
            af[m][0] = frag_ld(Ahs, row, lg);
            af[m][1] = frag_ld(Als, row, lg);
        }
        #pragma unroll
        for (int n = 0; n < 4; ++n) {
            int row = wc + n * 16 + l15;
            bfr[n][0] = frag_ld(Bhs, row, lg);
            bfr[n][1] = frag_ld(Bls, row, lg);
        }
        #pragma unroll
        for (int m = 0; m < 4; ++m)
            #pragma unroll
            for (int n = 0; n < 4; ++n) {
                acc[m][n] = __builtin_amdgcn_mfma_f32_16x16x32_bf16(af[m][0], bfr[n][0], acc[m][n], 0, 0, 0);
                acc[m][n] = __builtin_amdgcn_mfma_f32_16x16x32_bf16(af[m][0], bfr[n][1], acc[m][n], 0, 0, 0);
                acc[m][n] = __builtin_amdgcn_mfma_f32_16x16x32_bf16(af[m][1], bfr[n][0], acc[m][n], 0, 0, 0);
            }
    }

    #pragma unroll
    for (int m = 0; m < 4; ++m) {
        #pragma unroll
        for (int n = 0; n < 4; ++n) {
            #pragma unroll
            for (int q = 0; q < 4; ++q) {
                size_t gm = mblk + wr + m * 16 + lg * 4 + q;
                int    gn = nblk + wc + n * 16 + l15;
                Out[gm * DINNER + gn] = acc[m][n][q];
            }
        }
    }
}

// ---------------------------------------------------------------------------
// fp32 -> hi/lo bf16 split (weights), float4 grid-stride
// ---------------------------------------------------------------------------
__global__ void split_f32(const float* __restrict__ src, unsigned short* __restrict__ h,
                          unsigned short* __restrict__ l, int n4)
{
    int stride = gridDim.x * blockDim.x;
    for (int i = blockIdx.x * blockDim.x + threadIdx.x; i < n4; i += stride) {
        float4 v = reinterpret_cast<const float4*>(src)[i];
        unsigned short h0,h1,h2,h3,l0,l1,l2,l3;
        split2(v.x, h0, l0); split2(v.y, h1, l1);
        split2(v.z, h2, l2); split2(v.w, h3, l3);
        reinterpret_cast<ushort4*>(h)[i] = make_ushort4(h0,h1,h2,h3);
        reinterpret_cast<ushort4*>(l)[i] = make_ushort4(l0,l1,l2,l3);
    }
}

// ---------------------------------------------------------------------------
// Row-normalize Bm and Cm: row /= max(||row||, 1). One wave per (row, matrix).
// ---------------------------------------------------------------------------
__global__ void normalize_bc(float* __restrict__ Bm, float* __restrict__ Cm)
{
    int w    = (blockIdx.x * blockDim.x + threadIdx.x) >> 6;
    int lane = threadIdx.x & 63;
    int row  = w >> 1;
    float* M = (w & 1) ? Cm : Bm;
    float v = M[(size_t)row * DSTATE + lane];
    float s = v * v;
    #pragma unroll
    for (int off = 32; off; off >>= 1) s += __shfl_xor(s, off);
    float scale = 1.0f / fmaxf(sqrtf(s), 1.0f);
    M[(size_t)row * DSTATE + lane] = v * scale;
}

// ---------------------------------------------------------------------------
// Scan pass A: per-chunk (A_prod, P) summaries per channel.
// grid: (b,c,ib) = 4*32*4 = 512 blocks x 256 threads.
// ---------------------------------------------------------------------------
__global__ void scan_passA(const float* __restrict__ dt, const float* __restrict__ x_ssm,
                           const float* __restrict__ Bm, const float* __restrict__ A_log,
                           float* __restrict__ Asum, float* __restrict__ Psum)
{
    int bi = blockIdx.x;
    int ib = bi & 3;
    int c  = (bi >> 2) & (NC - 1);
    int b  = bi >> 7;
    int i  = ib * 256 + threadIdx.x;
    float aneg = -expf(A_log[i]);
    float Aacc = 1.0f, P = 0.0f;
    size_t rowbase = (size_t)b * SEQ + (size_t)c * CH;
    for (int t = 0; t < CH; ++t) {
        size_t off = (rowbase + t) * DINNER + i;
        float d  = dt[off];
        float x  = x_ssm[off];
        float Bv = Bm[(rowbase + t) * DSTATE + (i & 63)];
        float a  = expf(d * aneg);
        Aacc *= a;
        P = fmaf(a, P, d * Bv * x);
    }
    size_t so = ((size_t)b * NC + c) * DINNER + i;
    Asum[so] = Aacc; Psum[so] = P;
}

// ---------------------------------------------------------------------------
// Chunk-prefix: sequential over NC=32 chunk summaries per channel.
// ---------------------------------------------------------------------------
__global__ void scan_chunkprefix(const float* __restrict__ Asum,
                                 const float* __restrict__ Psum,
                                 float* __restrict__ H)
{
    int idx = blockIdx.x * blockDim.x + threadIdx.x; // 0..4095
    int b = idx >> 10, i = idx & 1023;
    float h = 0.0f;
    for (int c = 0; c < NC; ++c) {
        size_t so = ((size_t)b * NC + c) * DINNER + i;
        H[so] = h;
        h = fmaf(Asum[so], h, Psum[so]);
    }
}

// ---------------------------------------------------------------------------
// Scan pass B: replay with h_start; y = C*h + Dp*x_ssm, written pre-split
// as bf16 hi/lo (feeds out_gemm directly).
// ---------------------------------------------------------------------------
__global__ void scan_passB(const float* __restrict__ dt, const float* __restrict__ x_ssm,
                           const float* __restrict__ Bm, const float* __restrict__ Cm,
                           const float* __restrict__ A_log, const float* __restrict__ Dp,
                           const float* __restrict__ H,
                           unsigned short* __restrict__ Yh, unsigned short* __restrict__ Yl)
{
    int bi = blockIdx.x;
    int ib = bi & 3;
    int c  = (bi >> 2) & (NC - 1);
    int b  = bi >> 7;
    int i  = ib * 256 + threadIdx.x;
    float aneg = -expf(A_log[i]);
    float Dpi  = Dp[i];
    size_t so = ((size_t)b * NC + c) * DINNER + i;
    float h = H[so];
    size_t rowbase = (size_t)b * SEQ + (size_t)c * CH;
    for (int t = 0; t < CH; ++t) {
        size_t off = (rowbase + t) * DINNER + i;
        float d  = dt[off];
        float x  = x_ssm[off];
        float Bv = Bm[(rowbase + t) * DSTATE + (i & 63)];
        float Cv = Cm[(rowbase + t) * DSTATE + (i & 63)];
        float a  = expf(d * aneg);
        h = fmaf(a, h, d * Bv * x);
        float y = Cv * h + Dpi * x;
        unsigned short yh, yl;
        split2(y, yh, yl);
        Yh[off] = yh; Yl[off] = yl;
    }
}

// ---------------------------------------------------------------------------
extern "C" void kernel_launch(void* const* d_in, const int* in_sizes, int n_in,
                              void* d_out, int out_size, void* d_ws, size_t ws_size,
                              hipStream_t stream)
{
    const float* x_norm = (const float*)d_in[0];
    const float* Wx     = (const float*)d_in[1];
    const float* Wdt    = (const float*)d_in[2];
    const float* b_dt   = (const float*)d_in[3];
    const float* WB     = (const float*)d_in[4];
    const float* WC     = (const float*)d_in[5];
    const float* A_log  = (const float*)d_in[6];
    const float* Dp     = (const float*)d_in[7];
    const float* Wout   = (const float*)d_in[8];
    float* out = (float*)d_out;

    const size_t MB = 1024 * 1024;
    char* ws = (char*)d_ws;
    float* x_ssm = (float*)(ws);                         // [0,64) MB
    float* dtbuf = (float*)(ws + 64*MB);                 // [64,128) MB
    float* Bm    = (float*)(ws + 128*MB);                // 4 MB
    float* Cm    = (float*)(ws + 132*MB);                // 4 MB
    float* Asum  = (float*)(ws + 136*MB);                // 512 KB
    float* Psum  = (float*)(ws + 136*MB + 512*1024);     // 512 KB
    float* Hbuf  = (float*)(ws + 137*MB);                // 512 KB
    unsigned short* Wh  = (unsigned short*)(ws + 138*MB); // 8.5 MB (2176x2048)
    unsigned short* Wl  = (unsigned short*)(ws + 147*MB); // 8.5 MB
    unsigned short* Woh = (unsigned short*)(ws + 156*MB); // 2 MB (1024x1024)
    unsigned short* Wol = (unsigned short*)(ws + 158*MB); // 2 MB
    unsigned short* Yh  = (unsigned short*)(ws + 160*MB); // 32 MB (16384x1024)
    unsigned short* Yl  = (unsigned short*)(ws + 192*MB); // 32 MB  -> total 224 MB

    const size_t WXN = (size_t)DINNER * DMODEL;   // 2M elems
    const size_t WBN = (size_t)DSTATE * DMODEL;   // 128K elems

    // 1. split weights to hi/lo bf16 (packed W_all rows: Wx|Wdt|WB|WC)
    split_f32<<<1024, 256, 0, stream>>>(Wx,  Wh,             Wl,             (int)(WXN/4));
    split_f32<<<1024, 256, 0, stream>>>(Wdt, Wh + WXN,       Wl + WXN,       (int)(WXN/4));
    split_f32<<<64,   256, 0, stream>>>(WB,  Wh + 2*WXN,     Wl + 2*WXN,     (int)(WBN/4));
    split_f32<<<64,   256, 0, stream>>>(WC,  Wh + 2*WXN+WBN, Wl + 2*WXN+WBN, (int)(WBN/4));
    split_f32<<<1024, 256, 0, stream>>>(Wout, Woh, Wol, (int)((size_t)DINNER*DINNER/4));

    // 2. fused projection GEMM (softplus+clip fused into epilogue)
    proj_gemm<<<dim3(NPROJ/128, MTOT/128), 256, 0, stream>>>(
        x_norm, Wh, Wl, b_dt, x_ssm, dtbuf, Bm, Cm);
    // 3. normalize B,C rows
    normalize_bc<<<(MTOT*2)/4, 256, 0, stream>>>(Bm, Cm);
    // 4. chunk scan summaries
    scan_passA<<<BATCH*NC*(DINNER/256), 256, 0, stream>>>(
        dtbuf, x_ssm, Bm, A_log, Asum, Psum);
    // 5. chunk prefix
    scan_chunkprefix<<<(BATCH*DINNER)/256, 256, 0, stream>>>(Asum, Psum, Hbuf);
    // 6. replay; y written pre-split bf16 hi/lo
    scan_passB<<<BATCH*NC*(DINNER/256), 256, 0, stream>>>(
        dtbuf, x_ssm, Bm, Cm, A_log, Dp, Hbuf, Yh, Yl);
    // 7. output projection GEMM (pure pre-split bf16)
    out_gemm<<<dim3(DINNER/128, MTOT/128), 256, 0, stream>>>(
        Yh, Yl, Woh, Wol, out);
}